// Round 13
// baseline (570.746 us; speedup 1.0000x reference)
//
#include <hip/hip_runtime.h>
#include <hip/hip_bf16.h>
#include <cstdint>
#include <cstddef>

#define TT 128
#define BBATCH 256
#define FFEAT 76
#define HDIM 64
#define NHEAD 4
#define DKH 16
#define DFF1 256
#define AH1 8
#define NROWS (BBATCH * FFEAT)   // 19456
#define FCP 38                   // chunk size (2 chunks)

#define LOG2E 1.4426950408889634f

typedef __attribute__((ext_vector_type(8))) short bf16x8;
typedef __attribute__((ext_vector_type(4))) float f32x4;

__device__ __forceinline__ float fast_sigmoid(float v) {
    float p = __builtin_amdgcn_exp2f(-v * LOG2E);
    return __builtin_amdgcn_rcpf(1.0f + p);
}
__device__ __forceinline__ float fast_tanh(float v) {
    float p = __builtin_amdgcn_exp2f(v * (2.0f * LOG2E));
    return 1.0f - 2.0f * __builtin_amdgcn_rcpf(1.0f + p);
}
__device__ __forceinline__ short f2bf(float x) {
    __hip_bfloat16 h = __float2bfloat16(x);
    return *reinterpret_cast<short*>(&h);
}
__device__ __forceinline__ float bf2f(unsigned short s) {
    return __uint_as_float(((unsigned)s) << 16);
}
__device__ __forceinline__ unsigned pack_bf16(float a, float b) {
    unsigned ua = (unsigned)(unsigned short)f2bf(a);
    unsigned ub = (unsigned)(unsigned short)f2bf(b);
    return ua | (ub << 16);
}
// |h| <= 1 strictly (convex combo of tanh, h0=0) -> |h*127| <= 127, no clamp.
__device__ __forceinline__ unsigned pack_i8x4(float a, float b, float c, float d) {
    int ia = (int)rintf(a * 127.f);
    int ib = (int)rintf(b * 127.f);
    int ic = (int)rintf(c * 127.f);
    int id = (int)rintf(d * 127.f);
    return (unsigned)(ia & 255) | ((unsigned)(ib & 255) << 8)
         | ((unsigned)(ic & 255) << 16) | ((unsigned)id << 24);
}

// ---------------------------------------------------------------------------
// attention wave body (int8 hs): prefetch 16x8B, decode, R11 online-softmax,
// write emb row directly. wtil/emb alias (read-before-write per row, R10).
// ---------------------------------------------------------------------------
__device__ __forceinline__ void attn_wave_i8(
    const unsigned char* hs8, const float* wtil, const float* rate,
    int f, int f_loc, int b, int lane, float* emb)
{
    const int g = lane >> 3;
    const int i = lane & 7;
    const unsigned char* rb = hs8 + ((size_t)f_loc * BBATCH + b) * TT * 64;

    uint2 U[16];
    #pragma unroll
    for (int it = 0; it < 16; ++it)
        U[it] = *(const uint2*)(rb + ((size_t)(it * 8 + g) * 64 + i * 8));

    float wv[8];
    {
        const float4* src = (const float4*)(wtil + ((size_t)b * FFEAT + f) * HDIM + 8 * i);
        float4 a = src[0], c2 = src[1];
        wv[0]=a.x; wv[1]=a.y; wv[2]=a.z; wv[3]=a.w;
        wv[4]=c2.x; wv[5]=c2.y; wv[6]=c2.z; wv[7]=c2.w;
    }
    const float rs = fast_sigmoid(rate[f]);
    const float S = 1.0f / 127.0f;

    float m = -1.0e30f, s = 0.f;
    float o[8];
    #pragma unroll
    for (int j = 0; j < 8; ++j) o[j] = 0.f;

    #pragma unroll
    for (int it = 0; it < 16; ++it) {
        const int t = it * 8 + g;
        uint2 u = U[it];
        float h[8];
        h[0] = (float)(signed char)(u.x      ) * S;
        h[1] = (float)(signed char)(u.x >>  8) * S;
        h[2] = (float)(signed char)(u.x >> 16) * S;
        h[3] = (float)(signed char)(u.x >> 24) * S;
        h[4] = (float)(signed char)(u.y      ) * S;
        h[5] = (float)(signed char)(u.y >>  8) * S;
        h[6] = (float)(signed char)(u.y >> 16) * S;
        h[7] = (float)(signed char)(u.y >> 24) * S;
        float dp = 0.f;
        #pragma unroll
        for (int j = 0; j < 8; ++j) dp = fmaf(h[j], wv[j], dp);
        dp += __shfl_xor(dp, 1, 64);
        dp += __shfl_xor(dp, 2, 64);
        dp += __shfl_xor(dp, 4, 64);
        float sig = fast_sigmoid(dp);
        float den = rs * (__logf(2.72f + (1.0f - sig)) * (float)(TT - t));
        float e = fmaxf(sig / den, 0.0f);
        float nm = fmaxf(m, e);
        float sc = __builtin_amdgcn_exp2f((m - nm) * LOG2E);
        float p  = __builtin_amdgcn_exp2f((e - nm) * LOG2E);
        s = fmaf(s, sc, p);
        #pragma unroll
        for (int j = 0; j < 8; ++j) o[j] = fmaf(o[j], sc, p * h[j]);
        m = nm;
    }
    #pragma unroll
    for (int k = 8; k <= 32; k <<= 1) {
        float om = __shfl_xor(m, k, 64);
        float os = __shfl_xor(s, k, 64);
        float nm = fmaxf(m, om);
        float sa = __builtin_amdgcn_exp2f((m - nm) * LOG2E);
        float sb = __builtin_amdgcn_exp2f((om - nm) * LOG2E);
        s = s * sa + os * sb;
        #pragma unroll
        for (int j = 0; j < 8; ++j) {
            float oo = __shfl_xor(o[j], k, 64);
            o[j] = o[j] * sa + oo * sb;
        }
        m = nm;
    }
    if (g == 0) {
        float inv = __builtin_amdgcn_rcpf(s);
        float4 v0, v1;
        v0.x = o[0]*inv; v0.y = o[1]*inv; v0.z = o[2]*inv; v0.w = o[3]*inv;
        v1.x = o[4]*inv; v1.y = o[5]*inv; v1.z = o[6]*inv; v1.w = o[7]*inv;
        float* dst = &emb[((size_t)b * FFEAT + f) * HDIM + 8 * i];
        *(float4*)dst       = v0;
        *(float4*)(dst + 4) = v1;
    }
}

// ---------------------------------------------------------------------------
// FUSED kernel: gru role (R3 scan, int8 hs stores, wtilde epilogue) for the
// current chunk + attn role (attn_wave_i8) for the previous chunk. R8-proven:
// co-resident attn waves are free inside the gru latency window. natt=0 for
// the first launch.
// ---------------------------------------------------------------------------
__global__ __launch_bounds__(64) void fused_gru_attn_kernel(
    const float* __restrict__ x, const float* __restrict__ w_ih,
    const float* __restrict__ w_hh, const float* __restrict__ b_ih,
    const float* __restrict__ b_hh, const float* __restrict__ Wt,
    const float* __restrict__ Wx, const float* __restrict__ rate,
    int ngru, int f0_gru, unsigned char* __restrict__ hs_w,
    int f0_att, const unsigned char* __restrict__ hs_r,
    float* wtil_emb)
{
    __shared__ float x_lds[TT][16];
    __shared__ float wt_s[64][8];
    __shared__ float wx_s[64][8];
    __shared__ short hx[16][72];
    __shared__ float q_s[16][8];

    const int gid  = blockIdx.x;
    const int lane = threadIdx.x;

    if (gid < ngru) {
        // ---------------- GRU scan role ----------------
        const int f_loc = gid >> 4;
        const int f     = f0_gru + f_loc;
        const int b0    = (gid & 15) * 16;
        const int c     = lane & 15;
        const int q     = lane >> 4;

        for (int i = lane; i < TT * 16; i += 64) {
            int t = i >> 4, b = i & 15;
            x_lds[t][b] = x[((size_t)t * BBATCH + b0 + b) * FFEAT + f];
        }
        for (int i = lane; i < 512; i += 64) {
            ((float*)wt_s)[i] = Wt[(size_t)f * 512 + i];
            ((float*)wx_s)[i] = Wx[(size_t)f * 512 + i];
        }
        __syncthreads();

        bf16x8 afr[12][2];
        {
            const float* whh_f = w_hh + (size_t)f * 192 * 64;
            #pragma unroll
            for (int nt = 0; nt < 12; ++nt) {
                int gate = nt >> 2, tt = nt & 3;
                int urow = (c >> 2) * 8 + (tt & 1) * 4 + (c & 3) + (tt >> 1) * 32;
                const float* row = whh_f + (size_t)(gate * 64 + urow) * 64;
                #pragma unroll
                for (int kq = 0; kq < 2; ++kq) {
                    bf16x8 fr;
                    #pragma unroll
                    for (int j = 0; j < 8; ++j) fr[j] = f2bf(row[kq * 32 + q * 8 + j]);
                    afr[nt][kq] = fr;
                }
            }
        }
        float wr[4][4], wz[4][4], wn[4][4], bnx[4][4];
        f32x4 biasv[12];
        #pragma unroll
        for (int tt = 0; tt < 4; ++tt) {
            #pragma unroll
            for (int r = 0; r < 4; ++r) {
                int u = q * 8 + (tt & 1) * 4 + r + (tt >> 1) * 32;
                wr[tt][r]  = w_ih[f*192 + u];
                wz[tt][r]  = w_ih[f*192 + 64 + u];
                wn[tt][r]  = w_ih[f*192 + 128 + u];
                bnx[tt][r] = b_ih[f*192 + 128 + u];
                biasv[tt][r]     = b_ih[f*192 + u]      + b_hh[f*192 + u];
                biasv[4 + tt][r] = b_ih[f*192 + 64 + u] + b_hh[f*192 + 64 + u];
                biasv[8 + tt][r] = b_hh[f*192 + 128 + u];
            }
        }

        float hprev[4][4];
        #pragma unroll
        for (int tt = 0; tt < 4; ++tt)
            #pragma unroll
            for (int r = 0; r < 4; ++r) hprev[tt][r] = 0.f;

        bf16x8 hb0 = {0,0,0,0,0,0,0,0};
        bf16x8 hb1 = {0,0,0,0,0,0,0,0};

        unsigned char* hs_b = hs_w + ((size_t)f_loc * BBATCH + b0 + c) * TT * 64;

        for (int t = 0; t < TT; ++t) {
            f32x4 acc[12];
            #pragma unroll
            for (int nt = 0; nt < 12; ++nt) {
                f32x4 a = __builtin_amdgcn_mfma_f32_16x16x32_bf16(afr[nt][0], hb0, biasv[nt], 0, 0, 0);
                acc[nt]  = __builtin_amdgcn_mfma_f32_16x16x32_bf16(afr[nt][1], hb1, a, 0, 0, 0);
            }

            float xv = x_lds[t][c];
            float hn4[4][4];
            #pragma unroll
            for (int tt = 0; tt < 4; ++tt) {
                #pragma unroll
                for (int r = 0; r < 4; ++r) {
                    float R  = fmaf(xv, wr[tt][r], acc[tt][r]);
                    float Z  = fmaf(xv, wz[tt][r], acc[4 + tt][r]);
                    float NX = fmaf(xv, wn[tt][r], bnx[tt][r]);
                    float rg = fast_sigmoid(R);
                    float zg = fast_sigmoid(Z);
                    float ng = fast_tanh(fmaf(rg, acc[8 + tt][r], NX));
                    float hn = fmaf(zg, hprev[tt][r] - ng, ng);
                    hprev[tt][r] = hn;
                    hn4[tt][r] = hn;
                }
            }
            {   // bf16 pack for the recurrence (unchanged math)
                union { int4 i; bf16x8 v; } u0, u1;
                u0.i.x = pack_bf16(hn4[0][0], hn4[0][1]);
                u0.i.y = pack_bf16(hn4[0][2], hn4[0][3]);
                u0.i.z = pack_bf16(hn4[1][0], hn4[1][1]);
                u0.i.w = pack_bf16(hn4[1][2], hn4[1][3]);
                u1.i.x = pack_bf16(hn4[2][0], hn4[2][1]);
                u1.i.y = pack_bf16(hn4[2][2], hn4[2][3]);
                u1.i.z = pack_bf16(hn4[3][0], hn4[3][1]);
                u1.i.w = pack_bf16(hn4[3][2], hn4[3][3]);
                hb0 = u0.v; hb1 = u1.v;
            }
            {   // int8 store for the attention copy (halved traffic)
                uint2 s0, s1;
                s0.x = pack_i8x4(hn4[0][0], hn4[0][1], hn4[0][2], hn4[0][3]);
                s0.y = pack_i8x4(hn4[1][0], hn4[1][1], hn4[1][2], hn4[1][3]);
                s1.x = pack_i8x4(hn4[2][0], hn4[2][1], hn4[2][2], hn4[2][3]);
                s1.y = pack_i8x4(hn4[3][0], hn4[3][1], hn4[3][2], hn4[3][3]);
                unsigned char* dst = hs_b + (size_t)t * 64 + q * 8;
                *(uint2*)dst        = s0;
                *(uint2*)(dst + 32) = s1;
            }
        }

        *(bf16x8*)&hx[c][q * 8]      = hb0;
        *(bf16x8*)&hx[c][32 + q * 8] = hb1;

        #pragma unroll
        for (int rr = 0; rr < 2; ++rr) {
            int role = rr * 64 + lane;
            int b = role >> 3, a = role & 7;
            float s = 0.f;
            #pragma unroll 8
            for (int j = 0; j < 64; ++j)
                s = fmaf(bf2f((unsigned short)hx[b][j]), wt_s[j][a], s);
            q_s[b][a] = s;
        }
        {
            int b = lane >> 2, jb = (lane & 3) * 16;
            float qreg[8];
            #pragma unroll
            for (int a = 0; a < 8; ++a) qreg[a] = q_s[b][a];
            float* wt_out = wtil_emb + ((size_t)(b0 + b) * FFEAT + f) * HDIM + jb;
            #pragma unroll
            for (int j4 = 0; j4 < 4; ++j4) {
                float4 v;
                #pragma unroll
                for (int jj = 0; jj < 4; ++jj) {
                    int j = jb + j4 * 4 + jj;
                    float s = 0.f;
                    #pragma unroll
                    for (int a = 0; a < 8; ++a) s = fmaf(wx_s[j][a], qreg[a], s);
                    (&v.x)[jj] = s;
                }
                *(float4*)&wt_out[j4 * 4] = v;
            }
        }
    } else {
        // ---------------- attention role (prev chunk, 1 wave) ----------------
        const int aid   = gid - ngru;
        const int b     = aid & 255;
        const int f_loc = aid >> 8;
        attn_wave_i8(hs_r, wtil_emb, rate, f0_att + f_loc, f_loc, b, lane, wtil_emb);
    }
}

// standalone attention (drain launch), 4 waves/block
__global__ __launch_bounds__(256) void attn2_i8_kernel(
    const unsigned char* __restrict__ hs8, const float* wtil,
    const float* __restrict__ rate, int f_base, float* emb)
{
    const int w     = threadIdx.x >> 6;
    const int lane  = threadIdx.x & 63;
    const int b     = blockIdx.x * 4 + w;
    const int f_loc = blockIdx.y;
    attn_wave_i8(hs8, wtil, rate, f_base + f_loc, f_loc, b, lane, emb);
}

// ---------------------------------------------------------------------------
// Tail: tiled GEMM + MHA core + final head (proven split kernels, unchanged).
// ---------------------------------------------------------------------------
struct GemmP {
    const float* X;
    const float* W[3];
    const float* B[3];
    const float* R;
    float* Y[3];
    int K;
    int Nfull;
    int act;
};

__global__ __launch_bounds__(256) void gemm_kernel(GemmP A)
{
    __shared__ float xs[64][65];
    __shared__ float ws[64][68];

    const int tid = threadIdx.x;
    const int tx  = tid & 15;
    const int ty  = tid >> 4;
    const int m0  = blockIdx.x * 64;
    const int n0  = blockIdx.y * 64;
    const int z   = blockIdx.z;

    const float* W = A.W[z];
    const float* Bv = A.B[z];
    float* Y = A.Y[z];
    const int K = A.K, Nfull = A.Nfull;

    float acc[4][4];
    #pragma unroll
    for (int i = 0; i < 4; ++i)
        #pragma unroll
        for (int j = 0; j < 4; ++j) acc[i][j] = 0.f;

    for (int kc = 0; kc < K; kc += 64) {
        for (int s = tid; s < 1024; s += 256) {
            int row = s >> 4, c4 = s & 15;
            float4 xv = *(const float4*)&A.X[(size_t)(m0 + row) * K + kc + 4*c4];
            xs[row][4*c4+0] = xv.x; xs[row][4*c4+1] = xv.y;
            xs[row][4*c4+2] = xv.z; xs[row][4*c4+3] = xv.w;
            float4 wv = *(const float4*)&W[(size_t)(kc + row) * Nfull + n0 + 4*c4];
            *(float4*)&ws[row][4*c4] = wv;
        }
        __syncthreads();
        #pragma unroll 16
        for (int k = 0; k < 64; ++k) {
            float a0 = xs[4*ty+0][k], a1 = xs[4*ty+1][k];
            float a2 = xs[4*ty+2][k], a3 = xs[4*ty+3][k];
            float4 wv = *(const float4*)&ws[k][4*tx];
            #pragma unroll
            for (int j = 0; j < 4; ++j) {
                float wj = (&wv.x)[j];
                acc[0][j] = fmaf(a0, wj, acc[0][j]);
                acc[1][j] = fmaf(a1, wj, acc[1][j]);
                acc[2][j] = fmaf(a2, wj, acc[2][j]);
                acc[3][j] = fmaf(a3, wj, acc[3][j]);
            }
        }
        __syncthreads();
    }

    float4 bias = *(const float4*)&Bv[n0 + 4*tx];
    #pragma unroll
    for (int i = 0; i < 4; ++i) {
        int row = m0 + 4*ty + i;
        float4 v;
        v.x = acc[i][0] + bias.x; v.y = acc[i][1] + bias.y;
        v.z = acc[i][2] + bias.z; v.w = acc[i][3] + bias.w;
        if (A.act) {
            v.x = fmaxf(v.x, 0.f); v.y = fmaxf(v.y, 0.f);
            v.z = fmaxf(v.z, 0.f); v.w = fmaxf(v.w, 0.f);
        }
        if (A.R) {
            float4 r4 = *(const float4*)&A.R[(size_t)row * Nfull + n0 + 4*tx];
            v.x += r4.x; v.y += r4.y; v.z += r4.z; v.w += r4.w;
        }
        *(float4*)&Y[(size_t)row * Nfull + n0 + 4*tx] = v;
    }
}

__global__ __launch_bounds__(256) void mha_core_kernel(
    const float* __restrict__ q, const float* __restrict__ k,
    const float* __restrict__ v, float* __restrict__ ctx)
{
    const int b  = blockIdx.x;
    const int hh = blockIdx.y;
    const int tid = threadIdx.x;

    __shared__ float qs[FFEAT][17];
    __shared__ float ks[FFEAT][17];
    __shared__ float vs[FFEAT][17];
    __shared__ float ps[FFEAT][77];

    for (int idx = tid; idx < FFEAT * DKH; idx += 256) {
        int i = idx >> 4, c = idx & 15;
        size_t g = ((size_t)b * FFEAT + i) * HDIM + hh * DKH + c;
        qs[i][c] = q[g]; ks[i][c] = k[g]; vs[i][c] = v[g];
    }
    __syncthreads();

    for (int idx = tid; idx < FFEAT * FFEAT; idx += 256) {
        int i = idx / FFEAT, j = idx % FFEAT;
        float acc = 0.f;
        #pragma unroll
        for (int c = 0; c < DKH; ++c) acc = fmaf(qs[i][c], ks[j][c], acc);
        ps[i][j] = acc * 0.25f;
    }
    __syncthreads();

    if (tid < FFEAT) {
        float mm = ps[tid][0];
        #pragma unroll 4
        for (int j = 1; j < FFEAT; ++j) mm = fmaxf(mm, ps[tid][j]);
        float ss = 0.f;
        #pragma unroll 4
        for (int j = 0; j < FFEAT; ++j) {
            float pv = __builtin_amdgcn_exp2f((ps[tid][j] - mm) * LOG2E);
            ps[tid][j] = pv; ss += pv;
        }
        float inv = 1.0f / ss;
        #pragma unroll 4
        for (int j = 0; j < FFEAT; ++j) ps[tid][j] *= inv;
    }
    __syncthreads();

    for (int idx = tid; idx < FFEAT * DKH; idx += 256) {
        int i = idx >> 4, c = idx & 15;
        float acc = 0.f;
        #pragma unroll 4
        for (int j = 0; j < FFEAT; ++j) acc = fmaf(ps[i][j], vs[j][c], acc);
        ctx[((size_t)b * FFEAT + i) * HDIM + hh * DKH + c] = acc;
    }
}

__global__ __launch_bounds__(128) void final_kernel(
    const float* __restrict__ ctx3, const float* __restrict__ fk,
    const float* __restrict__ fv,
    const float* __restrict__ faq, const float* __restrict__ fabq,
    const float* __restrict__ o0w, const float* __restrict__ o0b,
    const float* __restrict__ o1w, const float* __restrict__ o1b,
    float* __restrict__ out)
{
    const int b = blockIdx.x;
    const int tid = threadIdx.x;

    __shared__ float last[HDIM];
    __shared__ float fqs[HDIM];
    __shared__ float sm[FFEAT];
    __shared__ float vv[HDIM];
    __shared__ float hh[HDIM];
    __shared__ float redm[2], redp[2];

    if (tid < HDIM) last[tid] = ctx3[((size_t)b * FFEAT + FFEAT - 1) * HDIM + tid];
    __syncthreads();
    if (tid < HDIM) {
        float acc = fabq[tid];
        #pragma unroll 8
        for (int j = 0; j < HDIM; ++j) acc = fmaf(last[j], faq[j * HDIM + tid], acc);
        fqs[tid] = acc;
    }
    __syncthreads();

    float e = -3.0e38f;
    if (tid < FFEAT) {
        const float4* kr = (const float4*)&fk[((size_t)b * FFEAT + tid) * HDIM];
        float acc = 0.f;
        #pragma unroll
        for (int c4 = 0; c4 < 16; ++c4) {
            float4 kv = kr[c4];
            acc = fmaf(kv.x, fqs[4*c4+0], acc);
            acc = fmaf(kv.y, fqs[4*c4+1], acc);
            acc = fmaf(kv.z, fqs[4*c4+2], acc);
            acc = fmaf(kv.w, fqs[4*c4+3], acc);
        }
        e = acc;
    }
    float m = e;
    #pragma unroll
    for (int off = 32; off > 0; off >>= 1) m = fmaxf(m, __shfl_xor(m, off, 64));
    if ((tid & 63) == 0) redm[tid >> 6] = m;
    __syncthreads();
    m = fmaxf(redm[0], redm[1]);
    float p = (tid < FFEAT) ? __builtin_amdgcn_exp2f((e - m) * LOG2E) : 0.f;
    float s = p;
    #pragma unroll
    for (int off = 32; off > 0; off >>= 1) s += __shfl_xor(s, off, 64);
    if ((tid & 63) == 0) redp[tid >> 6] = s;
    __syncthreads();
    s = redp[0] + redp[1];
    if (tid < FFEAT) sm[tid] = p / s;
    __syncthreads();

    if (tid < HDIM) {
        float acc = 0.f;
        for (int ff = 0; ff < FFEAT; ++ff)
            acc = fmaf(sm[ff], fv[((size_t)b * FFEAT + ff) * HDIM + tid], acc);
        vv[tid] = acc;
    }
    __syncthreads();
    if (tid < HDIM) {
        float acc = o0b[tid];
        #pragma unroll 8
        for (int j = 0; j < HDIM; ++j) acc = fmaf(vv[j], o0w[j * HDIM + tid], acc);
        hh[tid] = fmaxf(acc, 0.f);
    }
    __syncthreads();
    if (tid < 64) {
        float t = hh[tid] * o1w[tid];
        #pragma unroll
        for (int off = 32; off > 0; off >>= 1) t += __shfl_xor(t, off, 64);
        if (tid == 0) out[b] = fast_sigmoid(t + o1b[0]);
    }
}

__global__ void ws_report_kernel(float* out, int n, float ws_mib) {
    int i = blockIdx.x * blockDim.x + threadIdx.x;
    if (i < n) out[i] = ws_mib;
}

static void run_tail(const float* emb, float* ts,
                     const float* wq, const float* bq, const float* wk2, const float* bk2,
                     const float* wv2, const float* bv2, const float* wo, const float* bo,
                     const float* w1, const float* b1, const float* w2, const float* b2,
                     const float* faq, const float* fabq, const float* fak, const float* fabk,
                     const float* fav, const float* fabv, const float* o0w, const float* o0b,
                     const float* o1w, const float* o1b, float* out, hipStream_t stream)
{
    const size_t R64 = (size_t)NROWS * HDIM;
    float* q    = ts;
    float* k    = ts + 1*R64;
    float* v    = ts + 2*R64;
    float* ctx  = ts + 3*R64;
    float* ctx2 = ts + 4*R64;
    float* hid  = ts + 5*R64;
    float* ctx3 = ts + 9*R64;
    float* fk   = ts + 10*R64;
    float* fv   = ts + 11*R64;
    const int MB = NROWS / 64;

    {
        GemmP A = { emb, {wq, wk2, wv2}, {bq, bk2, bv2}, nullptr, {q, k, v}, 64, 64, 0 };
        gemm_kernel<<<dim3(MB, 1, 3), dim3(256), 0, stream>>>(A);
    }
    mha_core_kernel<<<dim3(BBATCH, NHEAD), dim3(256), 0, stream>>>(q, k, v, ctx);
    {
        GemmP A = { ctx, {wo, nullptr, nullptr}, {bo, nullptr, nullptr}, emb,
                    {ctx2, nullptr, nullptr}, 64, 64, 0 };
        gemm_kernel<<<dim3(MB, 1, 1), dim3(256), 0, stream>>>(A);
    }
    {
        GemmP A = { ctx2, {w1, nullptr, nullptr}, {b1, nullptr, nullptr}, nullptr,
                    {hid, nullptr, nullptr}, 64, 256, 1 };
        gemm_kernel<<<dim3(MB, 4, 1), dim3(256), 0, stream>>>(A);
    }
    {
        GemmP A = { hid, {w2, nullptr, nullptr}, {b2, nullptr, nullptr}, ctx2,
                    {ctx3, nullptr, nullptr}, 256, 64, 0 };
        gemm_kernel<<<dim3(MB, 1, 1), dim3(256), 0, stream>>>(A);
    }
    {
        GemmP A = { ctx3, {fak, fav, nullptr}, {fabk, fabv, nullptr}, nullptr,
                    {fk, fv, nullptr}, 64, 64, 0 };
        gemm_kernel<<<dim3(MB, 1, 2), dim3(256), 0, stream>>>(A);
    }
    final_kernel<<<dim3(BBATCH), dim3(128), 0, stream>>>(
        ctx3, fk, fv, faq, fabq, o0w, o0b, o1w, o1b, out);
}

extern "C" void kernel_launch(void* const* d_in, const int* in_sizes, int n_in,
                              void* d_out, int out_size, void* d_ws, size_t ws_size,
                              hipStream_t stream)
{
    const float* x     = (const float*)d_in[0];
    const float* w_ih  = (const float*)d_in[1];
    const float* w_hh  = (const float*)d_in[2];
    const float* b_ih  = (const float*)d_in[3];
    const float* b_hh  = (const float*)d_in[4];
    const float* attWt = (const float*)d_in[5];
    const float* attWx = (const float*)d_in[6];
    const float* attRt = (const float*)d_in[7];
    const float* wq    = (const float*)d_in[8];
    const float* bq    = (const float*)d_in[9];
    const float* wk    = (const float*)d_in[10];
    const float* bk    = (const float*)d_in[11];
    const float* wv    = (const float*)d_in[12];
    const float* bv    = (const float*)d_in[13];
    const float* wo    = (const float*)d_in[14];
    const float* bo    = (const float*)d_in[15];
    const float* w1    = (const float*)d_in[16];
    const float* b1    = (const float*)d_in[17];
    const float* w2    = (const float*)d_in[18];
    const float* b2    = (const float*)d_in[19];
    const float* faq   = (const float*)d_in[20];
    const float* fabq  = (const float*)d_in[21];
    const float* fak   = (const float*)d_in[22];
    const float* fabk  = (const float*)d_in[23];
    const float* fav   = (const float*)d_in[24];
    const float* fabv  = (const float*)d_in[25];
    const float* o0w   = (const float*)d_in[26];
    const float* o0b   = (const float*)d_in[27];
    const float* o1w   = (const float*)d_in[28];
    const float* o1b   = (const float*)d_in[29];
    float* out = (float*)d_out;

    const size_t emb_bytes = (size_t)NROWS * HDIM * 4;                // 4.98 MB
    const size_t hs8_half  = (size_t)FCP * BBATCH * TT * 64;          // 79.69 MB (int8)
    const size_t R64       = (size_t)NROWS * HDIM;
    const size_t tail_bytes = 12 * R64 * 4;                           // 59.8 MB

    float* wtil_emb = (float*)d_ws;                                   // [0, 4.98)
    unsigned char* hs0 = (unsigned char*)d_ws + emb_bytes;            // [4.98, 84.7)
    unsigned char* hs1 = hs0 + hs8_half;                              // [84.7, 164.4)
    float* ts = (float*)((char*)d_ws + emb_bytes);                    // tail scratch (hs dead)

    const size_t need_pipe = emb_bytes + 2 * hs8_half;                // 164.36 MB
    const size_t need_seq  = emb_bytes + (hs8_half > tail_bytes ? hs8_half : tail_bytes);

    if (ws_size >= need_pipe && emb_bytes + tail_bytes <= ws_size) {
        // -------- PIPELINED: gru(c0) -> gru(c1)||attn(c0) -> attn(c1) --------
        const int NG = 16 * FCP;        // 608 gru blocks
        const int NA = BBATCH * FCP;    // 9728 attn blocks
        fused_gru_attn_kernel<<<dim3(NG), dim3(64), 0, stream>>>(
            x, w_ih, w_hh, b_ih, b_hh, attWt, attWx, attRt,
            NG, 0, hs0, 0, hs1, wtil_emb);
        fused_gru_attn_kernel<<<dim3(NG + NA), dim3(64), 0, stream>>>(
            x, w_ih, w_hh, b_ih, b_hh, attWt, attWx, attRt,
            NG, FCP, hs1, 0, hs0, wtil_emb);
        attn2_i8_kernel<<<dim3(BBATCH / 4, FCP), dim3(256), 0, stream>>>(
            hs1, wtil_emb, attRt, FCP, wtil_emb);
        run_tail(wtil_emb, ts, wq, bq, wk, bk, wv, bv, wo, bo, w1, b1, w2, b2,
                 faq, fabq, fak, fabk, fav, fabv, o0w, o0b, o1w, o1b, out, stream);
        return;
    }

    if (ws_size >= need_seq) {
        // -------- SEQUENTIAL fallback: single int8 hs buffer --------
        for (int c = 0; c < 2; ++c) {
            fused_gru_attn_kernel<<<dim3(16 * FCP), dim3(64), 0, stream>>>(
                x, w_ih, w_hh, b_ih, b_hh, attWt, attWx, attRt,
                16 * FCP, c * FCP, hs0, 0, hs0, wtil_emb);
            attn2_i8_kernel<<<dim3(BBATCH / 4, FCP), dim3(256), 0, stream>>>(
                hs0, wtil_emb, attRt, c * FCP, wtil_emb);
        }
        run_tail(wtil_emb, ts, wq, bq, wk, bk, wv, bv, wo, bo, w1, b1, w2, b2,
                 faq, fabq, fak, fabk, fav, fabv, o0w, o0b, o1w, o1b, out, stream);
        return;
    }

    ws_report_kernel<<<dim3((out_size + 255) / 256), dim3(256), 0, stream>>>(
        out, out_size, (float)((double)ws_size / (1024.0 * 1024.0)));
}

// Round 14
// 563.590 us; speedup vs baseline: 1.0127x; 1.0127x over previous
//
#include <hip/hip_runtime.h>
#include <hip/hip_bf16.h>
#include <cstdint>
#include <cstddef>

#define TT 128
#define BBATCH 256
#define FFEAT 76
#define HDIM 64
#define NHEAD 4
#define DKH 16
#define DFF1 256
#define AH1 8
#define NROWS (BBATCH * FFEAT)   // 19456
#define FCP 38                   // chunk size (2 chunks)

#define LOG2E 1.4426950408889634f

typedef __attribute__((ext_vector_type(8))) short bf16x8;
typedef __attribute__((ext_vector_type(4))) float f32x4;

__device__ __forceinline__ float fast_sigmoid(float v) {
    float p = __builtin_amdgcn_exp2f(-v * LOG2E);
    return __builtin_amdgcn_rcpf(1.0f + p);
}
__device__ __forceinline__ float fast_tanh(float v) {
    float p = __builtin_amdgcn_exp2f(v * (2.0f * LOG2E));
    return 1.0f - 2.0f * __builtin_amdgcn_rcpf(1.0f + p);
}
__device__ __forceinline__ short f2bf(float x) {
    __hip_bfloat16 h = __float2bfloat16(x);
    return *reinterpret_cast<short*>(&h);
}
__device__ __forceinline__ float bf2f(unsigned short s) {
    return __uint_as_float(((unsigned)s) << 16);
}
__device__ __forceinline__ unsigned pack_bf16(float a, float b) {
    unsigned ua = (unsigned)(unsigned short)f2bf(a);
    unsigned ub = (unsigned)(unsigned short)f2bf(b);
    return ua | (ub << 16);
}
// Magic-number int8 pack: fmaf(h,127,1.5*2^23) -> round-nearest-even int8 in
// the low mantissa byte (|h|<1 strictly: GRU h is a convex combo of tanh).
// 4 FMA + byte merges, vs rint+cvt chains (R13's +19us scan tax).
__device__ __forceinline__ unsigned pack_i8x4m(float a, float b, float c, float d) {
    unsigned ua = __float_as_uint(fmaf(a, 127.f, 12582912.f));
    unsigned ub = __float_as_uint(fmaf(b, 127.f, 12582912.f));
    unsigned uc = __float_as_uint(fmaf(c, 127.f, 12582912.f));
    unsigned ud = __float_as_uint(fmaf(d, 127.f, 12582912.f));
    return (ua & 0xffu) | ((ub & 0xffu) << 8) | ((uc & 0xffu) << 16) | (ud << 24);
}

// ---------------------------------------------------------------------------
// attention wave bodies. wtil/emb alias (read-before-write per row, R10).
// ---------------------------------------------------------------------------
__device__ __forceinline__ void attn_wave_i8(
    const unsigned char* hs8, const float* wtil, const float* rate,
    int f, int f_loc, int b, int lane, float* emb)
{
    const int g = lane >> 3;
    const int i = lane & 7;
    const unsigned char* rb = hs8 + ((size_t)f_loc * BBATCH + b) * TT * 64;

    uint2 U[16];
    #pragma unroll
    for (int it = 0; it < 16; ++it)
        U[it] = *(const uint2*)(rb + ((size_t)(it * 8 + g) * 64 + i * 8));

    float wv[8];
    {
        const float4* src = (const float4*)(wtil + ((size_t)b * FFEAT + f) * HDIM + 8 * i);
        float4 a = src[0], c2 = src[1];
        wv[0]=a.x; wv[1]=a.y; wv[2]=a.z; wv[3]=a.w;
        wv[4]=c2.x; wv[5]=c2.y; wv[6]=c2.z; wv[7]=c2.w;
    }
    const float rs = fast_sigmoid(rate[f]);
    const float S = 1.0f / 127.0f;

    float m = -1.0e30f, s = 0.f;
    float o[8];
    #pragma unroll
    for (int j = 0; j < 8; ++j) o[j] = 0.f;

    #pragma unroll
    for (int it = 0; it < 16; ++it) {
        const int t = it * 8 + g;
        uint2 u = U[it];
        float h[8];
        h[0] = (float)(signed char)(u.x      ) * S;
        h[1] = (float)(signed char)(u.x >>  8) * S;
        h[2] = (float)(signed char)(u.x >> 16) * S;
        h[3] = (float)(signed char)(u.x >> 24) * S;
        h[4] = (float)(signed char)(u.y      ) * S;
        h[5] = (float)(signed char)(u.y >>  8) * S;
        h[6] = (float)(signed char)(u.y >> 16) * S;
        h[7] = (float)(signed char)(u.y >> 24) * S;
        float dp = 0.f;
        #pragma unroll
        for (int j = 0; j < 8; ++j) dp = fmaf(h[j], wv[j], dp);
        dp += __shfl_xor(dp, 1, 64);
        dp += __shfl_xor(dp, 2, 64);
        dp += __shfl_xor(dp, 4, 64);
        float sig = fast_sigmoid(dp);
        float den = rs * (__logf(2.72f + (1.0f - sig)) * (float)(TT - t));
        float e = fmaxf(sig / den, 0.0f);
        float nm = fmaxf(m, e);
        float sc = __builtin_amdgcn_exp2f((m - nm) * LOG2E);
        float p  = __builtin_amdgcn_exp2f((e - nm) * LOG2E);
        s = fmaf(s, sc, p);
        #pragma unroll
        for (int j = 0; j < 8; ++j) o[j] = fmaf(o[j], sc, p * h[j]);
        m = nm;
    }
    #pragma unroll
    for (int k = 8; k <= 32; k <<= 1) {
        float om = __shfl_xor(m, k, 64);
        float os = __shfl_xor(s, k, 64);
        float nm = fmaxf(m, om);
        float sa = __builtin_amdgcn_exp2f((m - nm) * LOG2E);
        float sb = __builtin_amdgcn_exp2f((om - nm) * LOG2E);
        s = s * sa + os * sb;
        #pragma unroll
        for (int j = 0; j < 8; ++j) {
            float oo = __shfl_xor(o[j], k, 64);
            o[j] = o[j] * sa + oo * sb;
        }
        m = nm;
    }
    if (g == 0) {
        float inv = __builtin_amdgcn_rcpf(s);
        float4 v0, v1;
        v0.x = o[0]*inv; v0.y = o[1]*inv; v0.z = o[2]*inv; v0.w = o[3]*inv;
        v1.x = o[4]*inv; v1.y = o[5]*inv; v1.z = o[6]*inv; v1.w = o[7]*inv;
        float* dst = &emb[((size_t)b * FFEAT + f) * HDIM + 8 * i];
        *(float4*)dst       = v0;
        *(float4*)(dst + 4) = v1;
    }
}

__device__ __forceinline__ void attn_wave_bf(
    const __hip_bfloat16* hs, const float* wtil, const float* rate,
    int f, int f_loc, int b, int lane, float* emb)
{
    const int g = lane >> 3;
    const int i = lane & 7;
    const uint4* basev = (const uint4*)((const short*)hs +
                          ((size_t)f_loc * BBATCH + b) * TT * HDIM);

    uint4 U[16];
    #pragma unroll
    for (int it = 0; it < 16; ++it)
        U[it] = basev[(it * 8 + g) * 8 + i];

    float wv[8];
    {
        const float4* src = (const float4*)(wtil + ((size_t)b * FFEAT + f) * HDIM + 8 * i);
        float4 a = src[0], c2 = src[1];
        wv[0]=a.x; wv[1]=a.y; wv[2]=a.z; wv[3]=a.w;
        wv[4]=c2.x; wv[5]=c2.y; wv[6]=c2.z; wv[7]=c2.w;
    }
    const float rs = fast_sigmoid(rate[f]);

    float m = -1.0e30f, s = 0.f;
    float o[8];
    #pragma unroll
    for (int j = 0; j < 8; ++j) o[j] = 0.f;

    #pragma unroll
    for (int it = 0; it < 16; ++it) {
        const int t = it * 8 + g;
        uint4 Uv = U[it];
        float h[8];
        h[0] = __uint_as_float(Uv.x << 16); h[1] = __uint_as_float(Uv.x & 0xffff0000u);
        h[2] = __uint_as_float(Uv.y << 16); h[3] = __uint_as_float(Uv.y & 0xffff0000u);
        h[4] = __uint_as_float(Uv.z << 16); h[5] = __uint_as_float(Uv.z & 0xffff0000u);
        h[6] = __uint_as_float(Uv.w << 16); h[7] = __uint_as_float(Uv.w & 0xffff0000u);
        float dp = 0.f;
        #pragma unroll
        for (int j = 0; j < 8; ++j) dp = fmaf(h[j], wv[j], dp);
        dp += __shfl_xor(dp, 1, 64);
        dp += __shfl_xor(dp, 2, 64);
        dp += __shfl_xor(dp, 4, 64);
        float sig = fast_sigmoid(dp);
        float den = rs * (__logf(2.72f + (1.0f - sig)) * (float)(TT - t));
        float e = fmaxf(sig / den, 0.0f);
        float nm = fmaxf(m, e);
        float sc = __builtin_amdgcn_exp2f((m - nm) * LOG2E);
        float p  = __builtin_amdgcn_exp2f((e - nm) * LOG2E);
        s = fmaf(s, sc, p);
        #pragma unroll
        for (int j = 0; j < 8; ++j) o[j] = fmaf(o[j], sc, p * h[j]);
        m = nm;
    }
    #pragma unroll
    for (int k = 8; k <= 32; k <<= 1) {
        float om = __shfl_xor(m, k, 64);
        float os = __shfl_xor(s, k, 64);
        float nm = fmaxf(m, om);
        float sa = __builtin_amdgcn_exp2f((m - nm) * LOG2E);
        float sb = __builtin_amdgcn_exp2f((om - nm) * LOG2E);
        s = s * sa + os * sb;
        #pragma unroll
        for (int j = 0; j < 8; ++j) {
            float oo = __shfl_xor(o[j], k, 64);
            o[j] = o[j] * sa + oo * sb;
        }
        m = nm;
    }
    if (g == 0) {
        float inv = __builtin_amdgcn_rcpf(s);
        float4 v0, v1;
        v0.x = o[0]*inv; v0.y = o[1]*inv; v0.z = o[2]*inv; v0.w = o[3]*inv;
        v1.x = o[4]*inv; v1.y = o[5]*inv; v1.z = o[6]*inv; v1.w = o[7]*inv;
        float* dst = &emb[((size_t)b * FFEAT + f) * HDIM + 8 * i];
        *(float4*)dst       = v0;
        *(float4*)(dst + 4) = v1;
    }
}

// ---------------------------------------------------------------------------
// Templated FUSED kernel: gru role (R3 scan + wtilde epilogue; SI8 selects
// int8 magic-pack store vs plain bf16 store) + attn role for the previous
// chunk (RI8 selects int8 vs bf16 read). R8/R13-proven: co-resident attn
// waves are free inside the gru latency window.
// ---------------------------------------------------------------------------
template<int SI8, int RI8>
__global__ __launch_bounds__(64) void fused_gru_attn_kernel(
    const float* __restrict__ x, const float* __restrict__ w_ih,
    const float* __restrict__ w_hh, const float* __restrict__ b_ih,
    const float* __restrict__ b_hh, const float* __restrict__ Wt,
    const float* __restrict__ Wx, const float* __restrict__ rate,
    int ngru, int f0_gru, void* __restrict__ hs_w,
    int f0_att, const void* __restrict__ hs_r,
    float* wtil_emb)
{
    __shared__ float x_lds[TT][16];
    __shared__ float wt_s[64][8];
    __shared__ float wx_s[64][8];
    __shared__ short hx[16][72];
    __shared__ float q_s[16][8];

    const int gid  = blockIdx.x;
    const int lane = threadIdx.x;

    if (gid < ngru) {
        const int f_loc = gid >> 4;
        const int f     = f0_gru + f_loc;
        const int b0    = (gid & 15) * 16;
        const int c     = lane & 15;
        const int q     = lane >> 4;

        for (int i = lane; i < TT * 16; i += 64) {
            int t = i >> 4, b = i & 15;
            x_lds[t][b] = x[((size_t)t * BBATCH + b0 + b) * FFEAT + f];
        }
        for (int i = lane; i < 512; i += 64) {
            ((float*)wt_s)[i] = Wt[(size_t)f * 512 + i];
            ((float*)wx_s)[i] = Wx[(size_t)f * 512 + i];
        }
        __syncthreads();

        bf16x8 afr[12][2];
        {
            const float* whh_f = w_hh + (size_t)f * 192 * 64;
            #pragma unroll
            for (int nt = 0; nt < 12; ++nt) {
                int gate = nt >> 2, tt = nt & 3;
                int urow = (c >> 2) * 8 + (tt & 1) * 4 + (c & 3) + (tt >> 1) * 32;
                const float* row = whh_f + (size_t)(gate * 64 + urow) * 64;
                #pragma unroll
                for (int kq = 0; kq < 2; ++kq) {
                    bf16x8 fr;
                    #pragma unroll
                    for (int j = 0; j < 8; ++j) fr[j] = f2bf(row[kq * 32 + q * 8 + j]);
                    afr[nt][kq] = fr;
                }
            }
        }
        float wr[4][4], wz[4][4], wn[4][4], bnx[4][4];
        f32x4 biasv[12];
        #pragma unroll
        for (int tt = 0; tt < 4; ++tt) {
            #pragma unroll
            for (int r = 0; r < 4; ++r) {
                int u = q * 8 + (tt & 1) * 4 + r + (tt >> 1) * 32;
                wr[tt][r]  = w_ih[f*192 + u];
                wz[tt][r]  = w_ih[f*192 + 64 + u];
                wn[tt][r]  = w_ih[f*192 + 128 + u];
                bnx[tt][r] = b_ih[f*192 + 128 + u];
                biasv[tt][r]     = b_ih[f*192 + u]      + b_hh[f*192 + u];
                biasv[4 + tt][r] = b_ih[f*192 + 64 + u] + b_hh[f*192 + 64 + u];
                biasv[8 + tt][r] = b_hh[f*192 + 128 + u];
            }
        }

        float hprev[4][4];
        #pragma unroll
        for (int tt = 0; tt < 4; ++tt)
            #pragma unroll
            for (int r = 0; r < 4; ++r) hprev[tt][r] = 0.f;

        bf16x8 hb0 = {0,0,0,0,0,0,0,0};
        bf16x8 hb1 = {0,0,0,0,0,0,0,0};

        unsigned char* hs8_b = (unsigned char*)hs_w +
                               ((size_t)f_loc * BBATCH + b0 + c) * TT * 64;
        short* hsb_b = (short*)hs_w + ((size_t)f_loc * BBATCH + b0 + c) * TT * HDIM;

        for (int t = 0; t < TT; ++t) {
            f32x4 acc[12];
            #pragma unroll
            for (int nt = 0; nt < 12; ++nt) {
                f32x4 a = __builtin_amdgcn_mfma_f32_16x16x32_bf16(afr[nt][0], hb0, biasv[nt], 0, 0, 0);
                acc[nt]  = __builtin_amdgcn_mfma_f32_16x16x32_bf16(afr[nt][1], hb1, a, 0, 0, 0);
            }

            float xv = x_lds[t][c];
            float hn4[4][4];
            #pragma unroll
            for (int tt = 0; tt < 4; ++tt) {
                #pragma unroll
                for (int r = 0; r < 4; ++r) {
                    float R  = fmaf(xv, wr[tt][r], acc[tt][r]);
                    float Z  = fmaf(xv, wz[tt][r], acc[4 + tt][r]);
                    float NX = fmaf(xv, wn[tt][r], bnx[tt][r]);
                    float rg = fast_sigmoid(R);
                    float zg = fast_sigmoid(Z);
                    float ng = fast_tanh(fmaf(rg, acc[8 + tt][r], NX));
                    float hn = fmaf(zg, hprev[tt][r] - ng, ng);
                    hprev[tt][r] = hn;
                    hn4[tt][r] = hn;
                }
            }
            {   // bf16 pack for the recurrence (always needed)
                union { int4 i; bf16x8 v; } u0, u1;
                u0.i.x = pack_bf16(hn4[0][0], hn4[0][1]);
                u0.i.y = pack_bf16(hn4[0][2], hn4[0][3]);
                u0.i.z = pack_bf16(hn4[1][0], hn4[1][1]);
                u0.i.w = pack_bf16(hn4[1][2], hn4[1][3]);
                u1.i.x = pack_bf16(hn4[2][0], hn4[2][1]);
                u1.i.y = pack_bf16(hn4[2][2], hn4[2][3]);
                u1.i.z = pack_bf16(hn4[3][0], hn4[3][1]);
                u1.i.w = pack_bf16(hn4[3][2], hn4[3][3]);
                hb0 = u0.v; hb1 = u1.v;
            }
            if constexpr (SI8) {
                uint2 s0, s1;
                s0.x = pack_i8x4m(hn4[0][0], hn4[0][1], hn4[0][2], hn4[0][3]);
                s0.y = pack_i8x4m(hn4[1][0], hn4[1][1], hn4[1][2], hn4[1][3]);
                s1.x = pack_i8x4m(hn4[2][0], hn4[2][1], hn4[2][2], hn4[2][3]);
                s1.y = pack_i8x4m(hn4[3][0], hn4[3][1], hn4[3][2], hn4[3][3]);
                unsigned char* dst = hs8_b + (size_t)t * 64 + q * 8;
                *(uint2*)dst        = s0;
                *(uint2*)(dst + 32) = s1;
            } else {
                short* dst = hsb_b + (size_t)t * HDIM + q * 8;
                *(bf16x8*)dst = hb0;
                *(bf16x8*)(dst + 32) = hb1;
            }
        }

        *(bf16x8*)&hx[c][q * 8]      = hb0;
        *(bf16x8*)&hx[c][32 + q * 8] = hb1;

        #pragma unroll
        for (int rr = 0; rr < 2; ++rr) {
            int role = rr * 64 + lane;
            int b = role >> 3, a = role & 7;
            float s = 0.f;
            #pragma unroll 8
            for (int j = 0; j < 64; ++j)
                s = fmaf(bf2f((unsigned short)hx[b][j]), wt_s[j][a], s);
            q_s[b][a] = s;
        }
        {
            int b = lane >> 2, jb = (lane & 3) * 16;
            float qreg[8];
            #pragma unroll
            for (int a = 0; a < 8; ++a) qreg[a] = q_s[b][a];
            float* wt_out = wtil_emb + ((size_t)(b0 + b) * FFEAT + f) * HDIM + jb;
            #pragma unroll
            for (int j4 = 0; j4 < 4; ++j4) {
                float4 v;
                #pragma unroll
                for (int jj = 0; jj < 4; ++jj) {
                    int j = jb + j4 * 4 + jj;
                    float s = 0.f;
                    #pragma unroll
                    for (int a = 0; a < 8; ++a) s = fmaf(wx_s[j][a], qreg[a], s);
                    (&v.x)[jj] = s;
                }
                *(float4*)&wt_out[j4 * 4] = v;
            }
        }
    } else {
        const int aid   = gid - ngru;
        const int b     = aid & 255;
        const int f_loc = aid >> 8;
        if constexpr (RI8)
            attn_wave_i8((const unsigned char*)hs_r, wtil_emb, rate,
                         f0_att + f_loc, f_loc, b, lane, wtil_emb);
        else
            attn_wave_bf((const __hip_bfloat16*)hs_r, wtil_emb, rate,
                         f0_att + f_loc, f_loc, b, lane, wtil_emb);
    }
}

// standalone bf16 attention (drain launch / tier-2), 4 waves/block
__global__ __launch_bounds__(256) void attn2_kernel(
    const __hip_bfloat16* __restrict__ hs, const float* wtil,
    const float* __restrict__ rate, int f_base, float* emb)
{
    const int w     = threadIdx.x >> 6;
    const int lane  = threadIdx.x & 63;
    const int b     = blockIdx.x * 4 + w;
    const int f_loc = blockIdx.y;
    attn_wave_bf(hs, wtil, rate, f_base + f_loc, f_loc, b, lane, emb);
}

// ---------------------------------------------------------------------------
// Tier-2 GRU scan (verbatim R11): bf16 hs + wtilde epilogue.
// ---------------------------------------------------------------------------
__global__ __launch_bounds__(64) void gru_scan_kernel(
    const float* __restrict__ x, const float* __restrict__ w_ih,
    const float* __restrict__ w_hh, const float* __restrict__ b_ih,
    const float* __restrict__ b_hh, const float* __restrict__ Wt,
    const float* __restrict__ Wx, int f_base,
    __hip_bfloat16* __restrict__ hs, float* __restrict__ wtil)
{
    const int f_loc = blockIdx.y;
    const int f     = f_base + f_loc;
    const int b0    = blockIdx.x * 16;
    const int lane  = threadIdx.x;
    const int c     = lane & 15;
    const int q     = lane >> 4;

    __shared__ float x_lds[TT][16];
    __shared__ float wt_s[64][8];
    __shared__ float wx_s[64][8];
    __shared__ short hx[16][72];
    __shared__ float q_s[16][8];

    for (int i = lane; i < TT * 16; i += 64) {
        int t = i >> 4, b = i & 15;
        x_lds[t][b] = x[((size_t)t * BBATCH + b0 + b) * FFEAT + f];
    }
    for (int i = lane; i < 512; i += 64) {
        ((float*)wt_s)[i] = Wt[(size_t)f * 512 + i];
        ((float*)wx_s)[i] = Wx[(size_t)f * 512 + i];
    }
    __syncthreads();

    bf16x8 afr[12][2];
    {
        const float* whh_f = w_hh + (size_t)f * 192 * 64;
        #pragma unroll
        for (int nt = 0; nt < 12; ++nt) {
            int gate = nt >> 2, tt = nt & 3;
            int urow = (c >> 2) * 8 + (tt & 1) * 4 + (c & 3) + (tt >> 1) * 32;
            const float* row = whh_f + (size_t)(gate * 64 + urow) * 64;
            #pragma unroll
            for (int kq = 0; kq < 2; ++kq) {
                bf16x8 fr;
                #pragma unroll
                for (int j = 0; j < 8; ++j) fr[j] = f2bf(row[kq * 32 + q * 8 + j]);
                afr[nt][kq] = fr;
            }
        }
    }
    float wr[4][4], wz[4][4], wn[4][4], bnx[4][4];
    f32x4 biasv[12];
    #pragma unroll
    for (int tt = 0; tt < 4; ++tt) {
        #pragma unroll
        for (int r = 0; r < 4; ++r) {
            int u = q * 8 + (tt & 1) * 4 + r + (tt >> 1) * 32;
            wr[tt][r]  = w_ih[f*192 + u];
            wz[tt][r]  = w_ih[f*192 + 64 + u];
            wn[tt][r]  = w_ih[f*192 + 128 + u];
            bnx[tt][r] = b_ih[f*192 + 128 + u];
            biasv[tt][r]     = b_ih[f*192 + u]      + b_hh[f*192 + u];
            biasv[4 + tt][r] = b_ih[f*192 + 64 + u] + b_hh[f*192 + 64 + u];
            biasv[8 + tt][r] = b_hh[f*192 + 128 + u];
        }
    }

    float hprev[4][4];
    #pragma unroll
    for (int tt = 0; tt < 4; ++tt)
        #pragma unroll
        for (int r = 0; r < 4; ++r) hprev[tt][r] = 0.f;

    bf16x8 hb0 = {0,0,0,0,0,0,0,0};
    bf16x8 hb1 = {0,0,0,0,0,0,0,0};

    short* hs_b = (short*)hs + ((size_t)f_loc * BBATCH + b0 + c) * TT * HDIM;

    for (int t = 0; t < TT; ++t) {
        f32x4 acc[12];
        #pragma unroll
        for (int nt = 0; nt < 12; ++nt) {
            f32x4 a = __builtin_amdgcn_mfma_f32_16x16x32_bf16(afr[nt][0], hb0, biasv[nt], 0, 0, 0);
            acc[nt]  = __builtin_amdgcn_mfma_f32_16x16x32_bf16(afr[nt][1], hb1, a, 0, 0, 0);
        }

        float xv = x_lds[t][c];
        float hn4[4][4];
        #pragma unroll
        for (int tt = 0; tt < 4; ++tt) {
            #pragma unroll
            for (int r = 0; r < 4; ++r) {
                float R  = fmaf(xv, wr[tt][r], acc[tt][r]);
                float Z  = fmaf(xv, wz[tt][r], acc[4 + tt][r]);
                float NX = fmaf(xv, wn[tt][r], bnx[tt][r]);
                float rg = fast_sigmoid(R);
                float zg = fast_sigmoid(Z);
                float ng = fast_tanh(fmaf(rg, acc[8 + tt][r], NX));
                float hn = fmaf(zg, hprev[tt][r] - ng, ng);
                hprev[tt][r] = hn;
                hn4[tt][r] = hn;
            }
        }
        {
            union { int4 i; bf16x8 v; } u0, u1;
            u0.i.x = pack_bf16(hn4[0][0], hn4[0][1]);
            u0.i.y = pack_bf16(hn4[0][2], hn4[0][3]);
            u0.i.z = pack_bf16(hn4[1][0], hn4[1][1]);
            u0.i.w = pack_bf16(hn4[1][2], hn4[1][3]);
            u1.i.x = pack_bf16(hn4[2][0], hn4[2][1]);
            u1.i.y = pack_bf16(hn4[2][2], hn4[2][3]);
            u1.i.z = pack_bf16(hn4[3][0], hn4[3][1]);
            u1.i.w = pack_bf16(hn4[3][2], hn4[3][3]);
            hb0 = u0.v; hb1 = u1.v;
        }
        short* dst = hs_b + (size_t)t * HDIM + q * 8;
        *(bf16x8*)dst = hb0;
        *(bf16x8*)(dst + 32) = hb1;
    }

    *(bf16x8*)&hx[c][q * 8]      = hb0;
    *(bf16x8*)&hx[c][32 + q * 8] = hb1;

    #pragma unroll
    for (int rr = 0; rr < 2; ++rr) {
        int role = rr * 64 + lane;
        int b = role >> 3, a = role & 7;
        float s = 0.f;
        #pragma unroll 8
        for (int j = 0; j < 64; ++j)
            s = fmaf(bf2f((unsigned short)hx[b][j]), wt_s[j][a], s);
        q_s[b][a] = s;
    }
    {
        int b = lane >> 2, jb = (lane & 3) * 16;
        float qreg[8];
        #pragma unroll
        for (int a = 0; a < 8; ++a) qreg[a] = q_s[b][a];
        float* wt_out = wtil + ((size_t)(b0 + b) * FFEAT + f) * HDIM + jb;
        #pragma unroll
        for (int j4 = 0; j4 < 4; ++j4) {
            float4 v;
            #pragma unroll
            for (int jj = 0; jj < 4; ++jj) {
                int j = jb + j4 * 4 + jj;
                float s = 0.f;
                #pragma unroll
                for (int a = 0; a < 8; ++a) s = fmaf(wx_s[j][a], qreg[a], s);
                (&v.x)[jj] = s;
            }
            *(float4*)&wt_out[j4 * 4] = v;
        }
    }
}

// ---------------------------------------------------------------------------
// Tail: tiled GEMM + MHA core + final head (proven split kernels, unchanged).
// ---------------------------------------------------------------------------
struct GemmP {
    const float* X;
    const float* W[3];
    const float* B[3];
    const float* R;
    float* Y[3];
    int K;
    int Nfull;
    int act;
};

__global__ __launch_bounds__(256) void gemm_kernel(GemmP A)
{
    __shared__ float xs[64][65];
    __shared__ float ws[64][68];

    const int tid = threadIdx.x;
    const int tx  = tid & 15;
    const int ty  = tid >> 4;
    const int m0  = blockIdx.x * 64;
    const int n0  = blockIdx.y * 64;
    const int z   = blockIdx.z;

    const float* W = A.W[z];
    const float* Bv = A.B[z];
    float* Y = A.Y[z];
    const int K = A.K, Nfull = A.Nfull;

    float acc[4][4];
    #pragma unroll
    for (int i = 0; i < 4; ++i)
        #pragma unroll
        for (int j = 0; j < 4; ++j) acc[i][j] = 0.f;

    for (int kc = 0; kc < K; kc += 64) {
        for (int s = tid; s < 1024; s += 256) {
            int row = s >> 4, c4 = s & 15;
            float4 xv = *(const float4*)&A.X[(size_t)(m0 + row) * K + kc + 4*c4];
            xs[row][4*c4+0] = xv.x; xs[row][4*c4+1] = xv.y;
            xs[row][4*c4+2] = xv.z; xs[row][4*c4+3] = xv.w;
            float4 wv = *(const float4*)&W[(size_t)(kc + row) * Nfull + n0 + 4*c4];
            *(float4*)&ws[row][4*c4] = wv;
        }
        __syncthreads();
        #pragma unroll 16
        for (int k = 0; k < 64; ++k) {
            float a0 = xs[4*ty+0][k], a1 = xs[4*ty+1][k];
            float a2 = xs[4*ty+2][k], a3 = xs[4*ty+3][k];
            float4 wv = *(const float4*)&ws[k][4*tx];
            #pragma unroll
            for (int j = 0; j < 4; ++j) {
                float wj = (&wv.x)[j];
                acc[0][j] = fmaf(a0, wj, acc[0][j]);
                acc[1][j] = fmaf(a1, wj, acc[1][j]);
                acc[2][j] = fmaf(a2, wj, acc[2][j]);
                acc[3][j] = fmaf(a3, wj, acc[3][j]);
            }
        }
        __syncthreads();
    }

    float4 bias = *(const float4*)&Bv[n0 + 4*tx];
    #pragma unroll
    for (int i = 0; i < 4; ++i) {
        int row = m0 + 4*ty + i;
        float4 v;
        v.x = acc[i][0] + bias.x; v.y = acc[i][1] + bias.y;
        v.z = acc[i][2] + bias.z; v.w = acc[i][3] + bias.w;
        if (A.act) {
            v.x = fmaxf(v.x, 0.f); v.y = fmaxf(v.y, 0.f);
            v.z = fmaxf(v.z, 0.f); v.w = fmaxf(v.w, 0.f);
        }
        if (A.R) {
            float4 r4 = *(const float4*)&A.R[(size_t)row * Nfull + n0 + 4*tx];
            v.x += r4.x; v.y += r4.y; v.z += r4.z; v.w += r4.w;
        }
        *(float4*)&Y[(size_t)row * Nfull + n0 + 4*tx] = v;
    }
}

__global__ __launch_bounds__(256) void mha_core_kernel(
    const float* __restrict__ q, const float* __restrict__ k,
    const float* __restrict__ v, float* __restrict__ ctx)
{
    const int b  = blockIdx.x;
    const int hh = blockIdx.y;
    const int tid = threadIdx.x;

    __shared__ float qs[FFEAT][17];
    __shared__ float ks[FFEAT][17];
    __shared__ float vs[FFEAT][17];
    __shared__ float ps[FFEAT][77];

    for (int idx = tid; idx < FFEAT * DKH; idx += 256) {
        int i = idx >> 4, c = idx & 15;
        size_t g = ((size_t)b * FFEAT + i) * HDIM + hh * DKH + c;
        qs[i][c] = q[g]; ks[i][c] = k[g]; vs[i][c] = v[g];
    }
    __syncthreads();

    for (int idx = tid; idx < FFEAT * FFEAT; idx += 256) {
        int i = idx / FFEAT, j = idx % FFEAT;
        float acc = 0.f;
        #pragma unroll
        for (int c = 0; c < DKH; ++c) acc = fmaf(qs[i][c], ks[j][c], acc);
        ps[i][j] = acc * 0.25f;
    }
    __syncthreads();

    if (tid < FFEAT) {
        float mm = ps[tid][0];
        #pragma unroll 4
        for (int j = 1; j < FFEAT; ++j) mm = fmaxf(mm, ps[tid][j]);
        float ss = 0.f;
        #pragma unroll 4
        for (int j = 0; j < FFEAT; ++j) {
            float pv = __builtin_amdgcn_exp2f((ps[tid][j] - mm) * LOG2E);
            ps[tid][j] = pv; ss += pv;
        }
        float inv = 1.0f / ss;
        #pragma unroll 4
        for (int j = 0; j < FFEAT; ++j) ps[tid][j] *= inv;
    }
    __syncthreads();

    for (int idx = tid; idx < FFEAT * DKH; idx += 256) {
        int i = idx >> 4, c = idx & 15;
        float acc = 0.f;
        #pragma unroll 4
        for (int j = 0; j < FFEAT; ++j) acc = fmaf(ps[i][j], vs[j][c], acc);
        ctx[((size_t)b * FFEAT + i) * HDIM + hh * DKH + c] = acc;
    }
}

__global__ __launch_bounds__(128) void final_kernel(
    const float* __restrict__ ctx3, const float* __restrict__ fk,
    const float* __restrict__ fv,
    const float* __restrict__ faq, const float* __restrict__ fabq,
    const float* __restrict__ o0w, const float* __restrict__ o0b,
    const float* __restrict__ o1w, const float* __restrict__ o1b,
    float* __restrict__ out)
{
    const int b = blockIdx.x;
    const int tid = threadIdx.x;

    __shared__ float last[HDIM];
    __shared__ float fqs[HDIM];
    __shared__ float sm[FFEAT];
    __shared__ float vv[HDIM];
    __shared__ float hh[HDIM];
    __shared__ float redm[2], redp[2];

    if (tid < HDIM) last[tid] = ctx3[((size_t)b * FFEAT + FFEAT - 1) * HDIM + tid];
    __syncthreads();
    if (tid < HDIM) {
        float acc = fabq[tid];
        #pragma unroll 8
        for (int j = 0; j < HDIM; ++j) acc = fmaf(last[j], faq[j * HDIM + tid], acc);
        fqs[tid] = acc;
    }
    __syncthreads();

    float e = -3.0e38f;
    if (tid < FFEAT) {
        const float4* kr = (const float4*)&fk[((size_t)b * FFEAT + tid) * HDIM];
        float acc = 0.f;
        #pragma unroll
        for (int c4 = 0; c4 < 16; ++c4) {
            float4 kv = kr[c4];
            acc = fmaf(kv.x, fqs[4*c4+0], acc);
            acc = fmaf(kv.y, fqs[4*c4+1], acc);
            acc = fmaf(kv.z, fqs[4*c4+2], acc);
            acc = fmaf(kv.w, fqs[4*c4+3], acc);
        }
        e = acc;
    }
    float m = e;
    #pragma unroll
    for (int off = 32; off > 0; off >>= 1) m = fmaxf(m, __shfl_xor(m, off, 64));
    if ((tid & 63) == 0) redm[tid >> 6] = m;
    __syncthreads();
    m = fmaxf(redm[0], redm[1]);
    float p = (tid < FFEAT) ? __builtin_amdgcn_exp2f((e - m) * LOG2E) : 0.f;
    float s = p;
    #pragma unroll
    for (int off = 32; off > 0; off >>= 1) s += __shfl_xor(s, off, 64);
    if ((tid & 63) == 0) redp[tid >> 6] = s;
    __syncthreads();
    s = redp[0] + redp[1];
    if (tid < FFEAT) sm[tid] = p / s;
    __syncthreads();

    if (tid < HDIM) {
        float acc = 0.f;
        for (int ff = 0; ff < FFEAT; ++ff)
            acc = fmaf(sm[ff], fv[((size_t)b * FFEAT + ff) * HDIM + tid], acc);
        vv[tid] = acc;
    }
    __syncthreads();
    if (tid < HDIM) {
        float acc = o0b[tid];
        #pragma unroll 8
        for (int j = 0; j < HDIM; ++j) acc = fmaf(vv[j], o0w[j * HDIM + tid], acc);
        hh[tid] = fmaxf(acc, 0.f);
    }
    __syncthreads();
    if (tid < 64) {
        float t = hh[tid] * o1w[tid];
        #pragma unroll
        for (int off = 32; off > 0; off >>= 1) t += __shfl_xor(t, off, 64);
        if (tid == 0) out[b] = fast_sigmoid(t + o1b[0]);
    }
}

__global__ void ws_report_kernel(float* out, int n, float ws_mib) {
    int i = blockIdx.x * blockDim.x + threadIdx.x;
    if (i < n) out[i] = ws_mib;
}

static void run_tail(const float* emb, float* ts,
                     const float* wq, const float* bq, const float* wk2, const float* bk2,
                     const float* wv2, const float* bv2, const float* wo, const float* bo,
                     const float* w1, const float* b1, const float* w2, const float* b2,
                     const float* faq, const float* fabq, const float* fak, const float* fabk,
                     const float* fav, const float* fabv, const float* o0w, const float* o0b,
                     const float* o1w, const float* o1b, float* out, hipStream_t stream)
{
    const size_t R64 = (size_t)NROWS * HDIM;
    float* q    = ts;
    float* k    = ts + 1*R64;
    float* v    = ts + 2*R64;
    float* ctx  = ts + 3*R64;
    float* ctx2 = ts + 4*R64;
    float* hid  = ts + 5*R64;
    float* ctx3 = ts + 9*R64;
    float* fk   = ts + 10*R64;
    float* fv   = ts + 11*R64;
    const int MB = NROWS / 64;

    {
        GemmP A = { emb, {wq, wk2, wv2}, {bq, bk2, bv2}, nullptr, {q, k, v}, 64, 64, 0 };
        gemm_kernel<<<dim3(MB, 1, 3), dim3(256), 0, stream>>>(A);
    }
    mha_core_kernel<<<dim3(BBATCH, NHEAD), dim3(256), 0, stream>>>(q, k, v, ctx);
    {
        GemmP A = { ctx, {wo, nullptr, nullptr}, {bo, nullptr, nullptr}, emb,
                    {ctx2, nullptr, nullptr}, 64, 64, 0 };
        gemm_kernel<<<dim3(MB, 1, 1), dim3(256), 0, stream>>>(A);
    }
    {
        GemmP A = { ctx2, {w1, nullptr, nullptr}, {b1, nullptr, nullptr}, nullptr,
                    {hid, nullptr, nullptr}, 64, 256, 1 };
        gemm_kernel<<<dim3(MB, 4, 1), dim3(256), 0, stream>>>(A);
    }
    {
        GemmP A = { hid, {w2, nullptr, nullptr}, {b2, nullptr, nullptr}, ctx2,
                    {ctx3, nullptr, nullptr}, 256, 64, 0 };
        gemm_kernel<<<dim3(MB, 1, 1), dim3(256), 0, stream>>>(A);
    }
    {
        GemmP A = { ctx3, {fak, fav, nullptr}, {fabk, fabv, nullptr}, nullptr,
                    {fk, fv, nullptr}, 64, 64, 0 };
        gemm_kernel<<<dim3(MB, 1, 2), dim3(256), 0, stream>>>(A);
    }
    final_kernel<<<dim3(BBATCH), dim3(128), 0, stream>>>(
        ctx3, fk, fv, faq, fabq, o0w, o0b, o1w, o1b, out);
}

extern "C" void kernel_launch(void* const* d_in, const int* in_sizes, int n_in,
                              void* d_out, int out_size, void* d_ws, size_t ws_size,
                              hipStream_t stream)
{
    const float* x     = (const float*)d_in[0];
    const float* w_ih  = (const float*)d_in[1];
    const float* w_hh  = (const float*)d_in[2];
    const float* b_ih  = (const float*)d_in[3];
    const float* b_hh  = (const float*)d_in[4];
    const float* attWt = (const float*)d_in[5];
    const float* attWx = (const float*)d_in[6];
    const float* attRt = (const float*)d_in[7];
    const float* wq    = (const float*)d_in[8];
    const float* bq    = (const float*)d_in[9];
    const float* wk    = (const float*)d_in[10];
    const float* bk    = (const float*)d_in[11];
    const float* wv    = (const float*)d_in[12];
    const float* bv    = (const float*)d_in[13];
    const float* wo    = (const float*)d_in[14];
    const float* bo    = (const float*)d_in[15];
    const float* w1    = (const float*)d_in[16];
    const float* b1    = (const float*)d_in[17];
    const float* w2    = (const float*)d_in[18];
    const float* b2    = (const float*)d_in[19];
    const float* faq   = (const float*)d_in[20];
    const float* fabq  = (const float*)d_in[21];
    const float* fak   = (const float*)d_in[22];
    const float* fabk  = (const float*)d_in[23];
    const float* fav   = (const float*)d_in[24];
    const float* fabv  = (const float*)d_in[25];
    const float* o0w   = (const float*)d_in[26];
    const float* o0b   = (const float*)d_in[27];
    const float* o1w   = (const float*)d_in[28];
    const float* o1b   = (const float*)d_in[29];
    float* out = (float*)d_out;

    const size_t emb_bytes = (size_t)NROWS * HDIM * 4;                // 4.98 MB
    const size_t hs8_half  = (size_t)FCP * BBATCH * TT * 64;          // 79.69 MB
    const size_t hsb_half  = hs8_half * 2;                            // 159.38 MB
    const size_t R64       = (size_t)NROWS * HDIM;
    const size_t tail_bytes = 12 * R64 * 4;                           // 59.8 MB

    const size_t need_t1 = emb_bytes + hs8_half + hsb_half;           // 244.05 MB

    if (ws_size >= need_t1) {
        // ---- TIER 1: asymmetric-precision pipeline ----
        float* wtil_emb = (float*)d_ws;
        unsigned char* hs0 = (unsigned char*)d_ws + emb_bytes;        // int8 chunk 0
        __hip_bfloat16* hs1 = (__hip_bfloat16*)(hs0 + hs8_half);      // bf16 chunk 1
        float* ts = (float*)((char*)d_ws + emb_bytes);

        const int NG = 16 * FCP;        // 608 gru blocks
        const int NA = BBATCH * FCP;    // 9728 attn blocks
        // L1: gru(c0) -> int8 (magic pack)
        fused_gru_attn_kernel<1, 0><<<dim3(NG), dim3(64), 0, stream>>>(
            x, w_ih, w_hh, b_ih, b_hh, attWt, attWx, attRt,
            NG, 0, hs0, 0, hs1, wtil_emb);
        // L2: gru(c1) -> bf16 (R3-speed)  ||  attn(c0) int8 (hidden)
        fused_gru_attn_kernel<0, 1><<<dim3(NG + NA), dim3(64), 0, stream>>>(
            x, w_ih, w_hh, b_ih, b_hh, attWt, attWx, attRt,
            NG, FCP, hs1, 0, hs0, wtil_emb);
        // L3: attn(c1) bf16 (proven R11 path)
        attn2_kernel<<<dim3(BBATCH / 4, FCP), dim3(256), 0, stream>>>(
            hs1, wtil_emb, attRt, FCP, wtil_emb);
        run_tail(wtil_emb, ts, wq, bq, wk, bk, wv, bv, wo, bo, w1, b1, w2, b2,
                 faq, fabq, fak, fabk, fav, fabv, o0w, o0b, o1w, o1b, out, stream);
        return;
    }

    // ---- TIER 2: verbatim R11 sequential (proven 564.7) ----
    const int chunk_opts[6] = {76, 38, 19, 4, 2, 1};
    int FC = 0;
    for (int i = 0; i < 6; ++i) {
        size_t hs_b = (size_t)chunk_opts[i] * BBATCH * TT * HDIM * 2;
        size_t scratch = hs_b > tail_bytes ? hs_b : tail_bytes;
        if (emb_bytes + scratch <= ws_size) { FC = chunk_opts[i]; break; }
    }
    if (FC == 0) {
        ws_report_kernel<<<dim3((out_size + 255) / 256), dim3(256), 0, stream>>>(
            out, out_size, (float)((double)ws_size / (1024.0 * 1024.0)));
        return;
    }

    float* embwtil = (float*)d_ws;
    char*  scratch = (char*)d_ws + emb_bytes;
    __hip_bfloat16* hs = (__hip_bfloat16*)scratch;

    for (int f0 = 0; f0 < FFEAT; f0 += FC) {
        int fc = (FFEAT - f0 < FC) ? (FFEAT - f0) : FC;
        gru_scan_kernel<<<dim3(16, fc), dim3(64), 0, stream>>>(
            x, w_ih, w_hh, b_ih, b_hh, attWt, attWx, f0, hs, embwtil);
        attn2_kernel<<<dim3(BBATCH / 4, fc), dim3(256), 0, stream>>>(
            hs, embwtil, attRt, f0, embwtil);
    }

    run_tail(embwtil, (float*)scratch, wq, bq, wk, bk, wv, bv, wo, bo, w1, b1, w2, b2,
             faq, fabq, fak, fabk, fav, fabv, o0w, o0b, o1w, o1b, out, stream);
}